// Round 13
// baseline (111.720 us; speedup 1.0000x reference)
//
#include <hip/hip_runtime.h>
#include <math.h>

#define N 8192
#define FIN 256
#define FOUT 64
#define ALPHA 0.2f
#define LOG2E 1.442695040888963f

typedef float f32x4 __attribute__((ext_vector_type(4)));
typedef _Float16 f16x8 __attribute__((ext_vector_type(8)));

union F16V { uint4 u; f16x8 h; };

__device__ __forceinline__ unsigned pack_f16(float a, float b) {
    union { _Float16 h; unsigned short u; } ca, cb;
    ca.h = (_Float16)a; cb.h = (_Float16)b;      // v_cvt_f16_f32, RNE
    return (unsigned)ca.u | ((unsigned)cb.u << 16);
}
// w' = exp(leaky(e)) * 2^-4  (scale cancels in softmax ratio; keeps f16 in range)
__device__ __forceinline__ float wcalc(int av, float fsr, float g) {
    float e = fsr + g;
    float le = e > 0.f ? e : ALPHA * e;
    float r = __builtin_exp2f(fmaf(le, LOG2E, -4.0f));
    return av != 0 ? r : 0.f;
}

// ---------------- Kernel 0: maskify — adj (256MB) -> mask8 (8MB), pure stream ----
// mask8[r*1024 + b] bit e = (adj[r][8b+e] != 0).  Thread reads 32B contiguous
// (int4 x2), writes 1 byte; wave reads 2KB fully-used lines, writes 64B.
__global__ __launch_bounds__(256) void gat_mask(
    const int* __restrict__ adj, unsigned char* __restrict__ mask8)
{
    const size_t tid = (size_t)blockIdx.x * 256 + threadIdx.x;  // 0..8M-1
    const int4 v0 = *reinterpret_cast<const int4*>(&adj[tid * 8]);
    const int4 v1 = *reinterpret_cast<const int4*>(&adj[tid * 8 + 4]);
    unsigned m = 0;
    m |= (v0.x != 0) ? 1u : 0u;
    m |= (v0.y != 0) ? 2u : 0u;
    m |= (v0.z != 0) ? 4u : 0u;
    m |= (v0.w != 0) ? 8u : 0u;
    m |= (v1.x != 0) ? 16u : 0u;
    m |= (v1.y != 0) ? 32u : 0u;
    m |= (v1.z != 0) ? 64u : 0u;
    m |= (v1.w != 0) ? 128u : 0u;
    mask8[tid] = (unsigned char)m;
}

// ---------------- Kernel 1: Wh = h@W -> fsrc/fdst + B_packed (pre-fragmented f16) ----
// Bp[(chunk*4+ft)*64 + lane] = f16(Wh[chunk*32+(lane>>4)*8+e][ft*16+(lane&15)])
__global__ __launch_bounds__(512) void gat_prep(
    const float* __restrict__ h, const float* __restrict__ W,
    const float* __restrict__ a,
    float* __restrict__ fsrc, float* __restrict__ fdst,
    uint4* __restrict__ Bp)
{
    __shared__ float sWh[32][FOUT + 1];
    const int t = threadIdx.x;
    const int f = t & 63;
    const int wq = t >> 6;
    const int row0 = blockIdx.x * 32;
    const int rbase = row0 + wq * 4;

    float acc[4] = {0.f, 0.f, 0.f, 0.f};
    for (int k0 = 0; k0 < FIN; k0 += 4) {
        const float w0 = W[(k0 + 0) * FOUT + f];
        const float w1 = W[(k0 + 1) * FOUT + f];
        const float w2 = W[(k0 + 2) * FOUT + f];
        const float w3 = W[(k0 + 3) * FOUT + f];
#pragma unroll
        for (int rr = 0; rr < 4; ++rr) {
            const float4 hv = *reinterpret_cast<const float4*>(
                &h[(size_t)(rbase + rr) * FIN + k0]);
            acc[rr] = fmaf(hv.x, w0, acc[rr]);
            acc[rr] = fmaf(hv.y, w1, acc[rr]);
            acc[rr] = fmaf(hv.z, w2, acc[rr]);
            acc[rr] = fmaf(hv.w, w3, acc[rr]);
        }
    }
    const float as = a[f], ad = a[FOUT + f];
#pragma unroll
    for (int rr = 0; rr < 4; ++rr) {
        sWh[wq * 4 + rr][f] = acc[rr];
        float fs = acc[rr] * as, fd = acc[rr] * ad;
#pragma unroll
        for (int off = 1; off < 64; off <<= 1) {
            fs += __shfl_xor(fs, off, 64);
            fd += __shfl_xor(fd, off, 64);
        }
        if (f == 0) { fsrc[rbase + rr] = fs; fdst[rbase + rr] = fd; }
    }
    __syncthreads();
    if (t < 256) {
        const int ft = t >> 6;
        const int l = t & 63;
        const int li = l & 15, g = l >> 4;
        float v[8];
#pragma unroll
        for (int e = 0; e < 8; ++e) v[e] = sWh[g * 8 + e][ft * 16 + li];
        uint4 pk;
        pk.x = pack_f16(v[0], v[1]);
        pk.y = pack_f16(v[2], v[3]);
        pk.z = pack_f16(v[4], v[5]);
        pk.w = pack_f16(v[6], v[7]);
        Bp[(size_t)(blockIdx.x * 4 + ft) * 64 + l] = pk;
    }
}

// ---------------- Kernel 2: barrier-free bitmask MFMA softmax-PV ----
// R8 structure (no LDS / no barriers in main loop, waves drift freely), with
// the A-side scatter fixed: per 32-col chunk, lane l loads 1 mask byte (its
// exact 8 bits, producer order == consumer order), 2 broadcast float4 fdst,
// 4 coalesced Bp fragments. All L2/L3-resident (adj stays in kernel 0).
struct Regs { unsigned m8; float4 g0, g1; uint4 b0, b1, b2, b3; };

__global__ __launch_bounds__(512, 4) void gat_main(
    const unsigned char* __restrict__ mask8,
    const uint4* __restrict__ Bp,
    const float* __restrict__ fsrc, const float* __restrict__ fdst,
    float* __restrict__ out)
{
    __shared__ float accbuf[8][4][64][4];  // 32 KB
    __shared__ float zbuf[8][16];
    __shared__ float Zfin[16];

    const int t = threadIdx.x;
    const int l = t & 63;
    const int w = t >> 6;
    const int row0 = blockIdx.x * 16;
    const int r = l & 15;
    const int g16 = l >> 4;                // 0..3
    const int kg8 = g16 << 3;
    const int jwbase = w * 1024;
    const int cgbase = w * 32;
    const float fsr = fsrc[row0 + r];
    const size_t mrow = (size_t)(row0 + r) * 1024 + (jwbase >> 3) + g16;

    f32x4 acc0 = {0.f, 0.f, 0.f, 0.f};
    f32x4 acc1 = {0.f, 0.f, 0.f, 0.f};
    f32x4 acc2 = {0.f, 0.f, 0.f, 0.f};
    f32x4 acc3 = {0.f, 0.f, 0.f, 0.f};
    float zacc = 0.f;
    Regs RA, RB;

#define LOADG(cl, S)                                                           \
    {                                                                          \
        const int j0_ = jwbase + (cl) * 32;                                    \
        S.m8 = mask8[mrow + (cl) * 4];                                         \
        S.g0 = *reinterpret_cast<const float4*>(&fdst[j0_ + kg8]);             \
        S.g1 = *reinterpret_cast<const float4*>(&fdst[j0_ + kg8 + 4]);         \
        const uint4* bp_ = Bp + (size_t)(cgbase + (cl)) * 4 * 64 + l;          \
        S.b0 = bp_[0];                                                         \
        S.b1 = bp_[64];                                                        \
        S.b2 = bp_[128];                                                       \
        S.b3 = bp_[192];                                                       \
    }

#define COMPUTE(S)                                                             \
    {                                                                          \
        const float w0 = wcalc((int)(S.m8 & 1u),   fsr, S.g0.x);               \
        const float w1 = wcalc((int)(S.m8 & 2u),   fsr, S.g0.y);               \
        const float w2 = wcalc((int)(S.m8 & 4u),   fsr, S.g0.z);               \
        const float w3 = wcalc((int)(S.m8 & 8u),   fsr, S.g0.w);               \
        const float w4 = wcalc((int)(S.m8 & 16u),  fsr, S.g1.x);               \
        const float w5 = wcalc((int)(S.m8 & 32u),  fsr, S.g1.y);               \
        const float w6 = wcalc((int)(S.m8 & 64u),  fsr, S.g1.z);               \
        const float w7 = wcalc((int)(S.m8 & 128u), fsr, S.g1.w);               \
        zacc += (w0 + w1) + (w2 + w3) + ((w4 + w5) + (w6 + w7));               \
        F16V av, b0v, b1v, b2v, b3v;                                           \
        av.u.x = pack_f16(w0, w1); av.u.y = pack_f16(w2, w3);                  \
        av.u.z = pack_f16(w4, w5); av.u.w = pack_f16(w6, w7);                  \
        b0v.u = S.b0; b1v.u = S.b1; b2v.u = S.b2; b3v.u = S.b3;                \
        __builtin_amdgcn_s_setprio(1);                                         \
        acc0 = __builtin_amdgcn_mfma_f32_16x16x32_f16(av.h, b0v.h, acc0, 0, 0, 0); \
        acc1 = __builtin_amdgcn_mfma_f32_16x16x32_f16(av.h, b1v.h, acc1, 0, 0, 0); \
        acc2 = __builtin_amdgcn_mfma_f32_16x16x32_f16(av.h, b2v.h, acc2, 0, 0, 0); \
        acc3 = __builtin_amdgcn_mfma_f32_16x16x32_f16(av.h, b3v.h, acc3, 0, 0, 0); \
        __builtin_amdgcn_s_setprio(0);                                         \
    }

    LOADG(0, RA);
    LOADG(1, RB);
    for (int c = 0; c < 32; c += 2) {
        COMPUTE(RA);
        if (c + 2 < 32) LOADG(c + 2, RA);
        COMPUTE(RB);
        if (c + 3 < 32) LOADG(c + 3, RB);
    }
#undef LOADG
#undef COMPUTE

    // ---- cross-wave reduction (R8-verified epilogue) ----
    zacc += __shfl_xor(zacc, 16, 64);
    zacc += __shfl_xor(zacc, 32, 64);
    if (l < 16) zbuf[w][l] = zacc;
    *reinterpret_cast<f32x4*>(&accbuf[w][0][l][0]) = acc0;
    *reinterpret_cast<f32x4*>(&accbuf[w][1][l][0]) = acc1;
    *reinterpret_cast<f32x4*>(&accbuf[w][2][l][0]) = acc2;
    *reinterpret_cast<f32x4*>(&accbuf[w][3][l][0]) = acc3;
    __syncthreads();
    if (t < 16) {
        float z = 0.f;
#pragma unroll
        for (int w2 = 0; w2 < 8; ++w2) z += zbuf[w2][t];
        Zfin[t] = z;
    }
    __syncthreads();

    // D layout (verified): col = lane&15, row = (lane>>4)*4 + reg
#pragma unroll
    for (int e0 = 0; e0 < 2; ++e0) {
        const int e = t + e0 * 512;
        const int rr = e >> 6, f2 = e & 63;
        const int c = f2 >> 4;
        const int ln = (f2 & 15) | ((rr >> 2) << 4);
        const int rg = rr & 3;
        float s = 0.f;
#pragma unroll
        for (int w2 = 0; w2 < 8; ++w2) s += accbuf[w2][c][ln][rg];
        const float hp = s / Zfin[rr];
        out[(size_t)(row0 + rr) * FOUT + f2] = hp > 0.f ? hp : expm1f(hp);
    }
}

extern "C" void kernel_launch(void* const* d_in, const int* in_sizes, int n_in,
                              void* d_out, int out_size, void* d_ws, size_t ws_size,
                              hipStream_t stream) {
    const float* h   = (const float*)d_in[0];
    const int*   adj = (const int*)d_in[1];
    const float* W   = (const float*)d_in[2];
    const float* a   = (const float*)d_in[3];
    float* out = (float*)d_out;

    float* ws = (float*)d_ws;
    float* fsrc = ws;                              // 8192 f32
    float* fdst = fsrc + N;                        // 8192 f32
    uint4* Bp = (uint4*)(fdst + N);                // 65536 uint4 = 1 MB
    unsigned char* mask8 = (unsigned char*)(Bp + 65536);   // 8 MB

    gat_mask<<<dim3((N / 8) * (N / 256)), dim3(256), 0, stream>>>(adj, mask8);
    gat_prep<<<dim3(N / 32), dim3(512), 0, stream>>>(h, W, a, fsrc, fdst, Bp);
    gat_main<<<dim3(N / 16), dim3(512), 0, stream>>>(mask8, Bp, fsrc, fdst, out);
}

// Round 14
// 93.528 us; speedup vs baseline: 1.1945x; 1.1945x over previous
//
#include <hip/hip_runtime.h>
#include <math.h>

#define N 8192
#define FIN 256
#define FOUT 64
#define ALPHA 0.2f
#define LOG2E 1.442695040888963f

#define JT 256                    // j-tile columns
#define NTILE (N / JT)            // 32
#define ROWPITCH 512              // bytes per A-LDS row (256 f16)
#define ABUF (16 * ROWPITCH)      // 8192 B per buffer
#define SMEM_BYTES (2 * ABUF)     // 16384

typedef float f32x4 __attribute__((ext_vector_type(4)));
typedef _Float16 f16x8 __attribute__((ext_vector_type(8)));

union F16V { uint4 u; f16x8 h; };

__device__ __forceinline__ unsigned pack_f16(float a, float b) {
    union { _Float16 h; unsigned short u; } ca, cb;
    ca.h = (_Float16)a; cb.h = (_Float16)b;      // v_cvt_f16_f32, RNE
    return (unsigned)ca.u | ((unsigned)cb.u << 16);
}
// w' = exp(leaky(e)) * 2^-4  (scale cancels in softmax ratio; keeps f16 in range)
__device__ __forceinline__ float wcalc(int av, float fsr, float g) {
    float e = fsr + g;
    float le = e > 0.f ? e : ALPHA * e;
    float r = __builtin_exp2f(fmaf(le, LOG2E, -4.0f));
    return av != 0 ? r : 0.f;
}

// ---------------- Kernel 1: Wh = h@W -> fsrc/fdst + B_packed (pre-fragmented f16) ----
// Bp[(chunk*4+ft)*64 + lane] = f16(Wh[chunk*32+(lane>>4)*8+e][ft*16+(lane&15)])
__global__ __launch_bounds__(512) void gat_prep(
    const float* __restrict__ h, const float* __restrict__ W,
    const float* __restrict__ a,
    float* __restrict__ fsrc, float* __restrict__ fdst,
    uint4* __restrict__ Bp)
{
    __shared__ float sWh[32][FOUT + 1];
    const int t = threadIdx.x;
    const int f = t & 63;
    const int wq = t >> 6;
    const int row0 = blockIdx.x * 32;
    const int rbase = row0 + wq * 4;

    float acc[4] = {0.f, 0.f, 0.f, 0.f};
    for (int k0 = 0; k0 < FIN; k0 += 4) {
        const float w0 = W[(k0 + 0) * FOUT + f];
        const float w1 = W[(k0 + 1) * FOUT + f];
        const float w2 = W[(k0 + 2) * FOUT + f];
        const float w3 = W[(k0 + 3) * FOUT + f];
#pragma unroll
        for (int rr = 0; rr < 4; ++rr) {
            const float4 hv = *reinterpret_cast<const float4*>(
                &h[(size_t)(rbase + rr) * FIN + k0]);
            acc[rr] = fmaf(hv.x, w0, acc[rr]);
            acc[rr] = fmaf(hv.y, w1, acc[rr]);
            acc[rr] = fmaf(hv.z, w2, acc[rr]);
            acc[rr] = fmaf(hv.w, w3, acc[rr]);
        }
    }
    const float as = a[f], ad = a[FOUT + f];
#pragma unroll
    for (int rr = 0; rr < 4; ++rr) {
        sWh[wq * 4 + rr][f] = acc[rr];
        float fs = acc[rr] * as, fd = acc[rr] * ad;
#pragma unroll
        for (int off = 1; off < 64; off <<= 1) {
            fs += __shfl_xor(fs, off, 64);
            fd += __shfl_xor(fd, off, 64);
        }
        if (f == 0) { fsrc[rbase + rr] = fs; fdst[rbase + rr] = fd; }
    }
    __syncthreads();
    if (t < 256) {
        const int ft = t >> 6;
        const int l = t & 63;
        const int li = l & 15, g = l >> 4;
        float v[8];
#pragma unroll
        for (int e = 0; e < 8; ++e) v[e] = sWh[g * 8 + e][ft * 16 + li];
        uint4 pk;
        pk.x = pack_f16(v[0], v[1]);
        pk.y = pack_f16(v[2], v[3]);
        pk.z = pack_f16(v[4], v[5]);
        pk.w = pack_f16(v[6], v[7]);
        Bp[(size_t)(blockIdx.x * 4 + ft) * 64 + l] = pk;
    }
}

// ---------------- Kernel 2: A-only-LDS MFMA flash softmax-PV, depth-2 AG ----
// R11 structure + dual AG register sets: AG(T) is issued two phases before
// STAGE(T) consumes it (~3000 cy cover vs ~900 cy HBM latency). Raw s_barrier
// + lgkmcnt(0)-only waits keep the vmcnt FIFO counted across barriers.
struct AdjG { int4 a0, a1; float4 g0, g1; };

__global__ __launch_bounds__(512, 4) void gat_main(
    const int* __restrict__ adj,
    const uint4* __restrict__ Bp,
    const float* __restrict__ fsrc, const float* __restrict__ fdst,
    float* __restrict__ out)
{
    __shared__ __align__(16) char smem[SMEM_BYTES];

    const int t = threadIdx.x;
    const int l = t & 63;
    const int w = t >> 6;
    const int row0 = blockIdx.x * 16;

    // --- staging map (contiguous adj) ---
    const int srow = t >> 5;               // 0..15
    const int sc8 = (t & 31) * 8;          // col (elements)
    const float fsr = fsrc[row0 + srow];
    const size_t adjrow = (size_t)(row0 + srow) * N;
    const int awo = srow * ROWPITCH + (((t & 31) * 16) ^ ((srow & 7) << 4));

    // --- MFMA map ---
    const int ft = w & 3;
    const int p = w >> 2;
    const int r16 = l & 15;
    const int kg8 = (l >> 4) << 3;
    const int fswz = (r16 & 7) << 4;
    const int aro = r16 * ROWPITCH;
    // Bp index (uint4): tile*2048 + p*1024 + ks*256 + ft*64 + lane
    const uint4* Bq = Bp + (size_t)p * 1024 + ft * 64 + l;

    f32x4 acc = {0.f, 0.f, 0.f, 0.f};
    float zacc = 0.f;
    AdjG GA, GB;
    uint4 BA0, BA1, BA2, BA3, BB0, BB1, BB2, BB3;

#define BAR                                                                    \
    {                                                                          \
        asm volatile("s_waitcnt lgkmcnt(0)" ::: "memory");                     \
        __builtin_amdgcn_s_barrier();                                          \
    }

#define LOAD_ADJG(tile, S)                                                     \
    {                                                                          \
        const int j0_ = (tile) * JT;                                           \
        S.a0 = *reinterpret_cast<const int4*>(&adj[adjrow + j0_ + sc8]);       \
        S.a1 = *reinterpret_cast<const int4*>(&adj[adjrow + j0_ + sc8 + 4]);   \
        S.g0 = *reinterpret_cast<const float4*>(&fdst[j0_ + sc8]);             \
        S.g1 = *reinterpret_cast<const float4*>(&fdst[j0_ + sc8 + 4]);         \
    }

#define LOAD_B(tile, B0, B1, B2, B3)                                           \
    {                                                                          \
        const uint4* bq_ = Bq + (size_t)(tile) * 2048;                         \
        B0 = bq_[0];                                                           \
        B1 = bq_[256];                                                         \
        B2 = bq_[512];                                                         \
        B3 = bq_[768];                                                         \
    }

#define STAGE(S, BUF)                                                          \
    {                                                                          \
        const float w0 = wcalc(S.a0.x, fsr, S.g0.x);                           \
        const float w1 = wcalc(S.a0.y, fsr, S.g0.y);                           \
        const float w2 = wcalc(S.a0.z, fsr, S.g0.z);                           \
        const float w3 = wcalc(S.a0.w, fsr, S.g0.w);                           \
        const float w4 = wcalc(S.a1.x, fsr, S.g1.x);                           \
        const float w5 = wcalc(S.a1.y, fsr, S.g1.y);                           \
        const float w6 = wcalc(S.a1.z, fsr, S.g1.z);                           \
        const float w7 = wcalc(S.a1.w, fsr, S.g1.w);                           \
        zacc += (w0 + w1) + (w2 + w3) + ((w4 + w5) + (w6 + w7));               \
        uint4 pk;                                                              \
        pk.x = pack_f16(w0, w1); pk.y = pack_f16(w2, w3);                      \
        pk.z = pack_f16(w4, w5); pk.w = pack_f16(w6, w7);                      \
        *reinterpret_cast<uint4*>(smem + (BUF) * ABUF + awo) = pk;             \
    }

#define MFMA_PHASE(BUF, B0, B1, B2, B3)                                        \
    {                                                                          \
        const char* ab_ = smem + (BUF) * ABUF + aro;                           \
        F16V a0v, a1v, a2v, a3v, b0v, b1v, b2v, b3v;                           \
        a0v.u = *reinterpret_cast<const uint4*>(ab_ + (((p * 128 + 0 * 32 + kg8) * 2) ^ fswz)); \
        a1v.u = *reinterpret_cast<const uint4*>(ab_ + (((p * 128 + 1 * 32 + kg8) * 2) ^ fswz)); \
        a2v.u = *reinterpret_cast<const uint4*>(ab_ + (((p * 128 + 2 * 32 + kg8) * 2) ^ fswz)); \
        a3v.u = *reinterpret_cast<const uint4*>(ab_ + (((p * 128 + 3 * 32 + kg8) * 2) ^ fswz)); \
        b0v.u = B0; b1v.u = B1; b2v.u = B2; b3v.u = B3;                        \
        __builtin_amdgcn_s_setprio(1);                                         \
        acc = __builtin_amdgcn_mfma_f32_16x16x32_f16(a0v.h, b0v.h, acc, 0, 0, 0); \
        acc = __builtin_amdgcn_mfma_f32_16x16x32_f16(a1v.h, b1v.h, acc, 0, 0, 0); \
        acc = __builtin_amdgcn_mfma_f32_16x16x32_f16(a2v.h, b2v.h, acc, 0, 0, 0); \
        acc = __builtin_amdgcn_mfma_f32_16x16x32_f16(a3v.h, b3v.h, acc, 0, 0, 0); \
        __builtin_amdgcn_s_setprio(0);                                         \
    }

    // ---- prologue: AG(0)->GA, B(0)->BA, AG(1)->GB, stage tile0, AG(2)->GA ----
    LOAD_ADJG(0, GA);
    LOAD_B(0, BA0, BA1, BA2, BA3);
    LOAD_ADJG(1, GB);
    STAGE(GA, 0);              // waits AG(0) only (oldest in FIFO)
    LOAD_ADJG(2, GA);
    BAR;

    for (int tt = 0; tt < NTILE; tt += 2) {
        // even phase T=tt: MFMA(tt) on buf0/BA; stage tile tt+1 from GB
        if (tt + 1 < NTILE) LOAD_B(tt + 1, BB0, BB1, BB2, BB3);
        MFMA_PHASE(0, BA0, BA1, BA2, BA3);      // waits B(tt); AG(tt+2), B(tt+1) stay in flight
        if (tt + 1 < NTILE) STAGE(GB, 1);       // waits AG(tt+1): issued 2 phases ago
        if (tt + 3 < NTILE) LOAD_ADJG(tt + 3, GB);
        BAR;
        // odd phase T=tt+1: MFMA(tt+1) on buf1/BB; stage tile tt+2 from GA
        if (tt + 2 < NTILE) LOAD_B(tt + 2, BA0, BA1, BA2, BA3);
        if (tt + 1 < NTILE) MFMA_PHASE(1, BB0, BB1, BB2, BB3);
        if (tt + 2 < NTILE) STAGE(GA, 0);       // waits AG(tt+2): issued 2 phases ago
        if (tt + 4 < NTILE) LOAD_ADJG(tt + 4, GA);
        BAR;
    }
#undef LOAD_ADJG
#undef LOAD_B
#undef STAGE
#undef MFMA_PHASE
#undef BAR

    __syncthreads();           // drain last MFMA reads before aliasing LDS

    // ---- Z + cross-parity reduction, epilogue ----
    float* zb = reinterpret_cast<float*>(smem + 8192);
    {
        float z = zacc;
#pragma unroll
        for (int off = 1; off < 32; off <<= 1) z += __shfl_xor(z, off, 64);
        if ((l & 31) == 0) zb[srow] = z;
    }
    *reinterpret_cast<f32x4*>(smem + w * 1024 + l * 16) = acc;
    __syncthreads();
#pragma unroll
    for (int e0 = 0; e0 < 2; ++e0) {
        const int e = t + e0 * 512;
        const int rr = e >> 6, f2 = e & 63;
        const int ft2 = f2 >> 4, n = f2 & 15;
        const int ln = n | ((rr >> 2) << 4);
        const int rg = rr & 3;
        const float s =
            *reinterpret_cast<const float*>(smem + ft2 * 1024 + ln * 16 + rg * 4) +
            *reinterpret_cast<const float*>(smem + (ft2 + 4) * 1024 + ln * 16 + rg * 4);
        const float hp = s / zb[rr];
        out[(size_t)(row0 + rr) * FOUT + f2] = hp > 0.f ? hp : expm1f(hp);
    }
}

extern "C" void kernel_launch(void* const* d_in, const int* in_sizes, int n_in,
                              void* d_out, int out_size, void* d_ws, size_t ws_size,
                              hipStream_t stream) {
    const float* h   = (const float*)d_in[0];
    const int*   adj = (const int*)d_in[1];
    const float* W   = (const float*)d_in[2];
    const float* a   = (const float*)d_in[3];
    float* out = (float*)d_out;

    float* ws = (float*)d_ws;
    float* fsrc = ws;
    float* fdst = fsrc + N;
    uint4* Bp = (uint4*)(fdst + N);        // FOUT*N f16 = 1 MB, pre-fragmented

    gat_prep<<<dim3(N / 32), dim3(512), 0, stream>>>(h, W, a, fsrc, fdst, Bp);
    gat_main<<<dim3(N / 16), dim3(512), 0, stream>>>(adj, Bp, fsrc, fdst, out);
}